// Round 11
// baseline (582.901 us; speedup 1.0000x reference)
//
#include <hip/hip_runtime.h>
#include <hip/hip_bf16.h>

#define EPS_BN 1e-5f

// Compiler fence: memory ops cannot cross it in either direction.
// HISTORY (do not regress):
//   r1: no fence                      -> pipeline collapsed (VGPR 36-48).
//   r2: fence + (256,2)               -> VGPR 128 spill-free iff footprint<=128.
//   r3: (256,4)                       -> allocator rounds DOWN to 64, 1GB spill.
//   r4: fenced streaming (256,2) = 586us.
//   r5: LDS read-once + K-loop barriers = lockstep-bound.
//   r6: __shfl dedup = ds_bpermute crossbar storm.
//   r7: column-per-thread OS=64 -> 1.9GB spill.
//   r8: OT=8/16 spill-free, 585us. OT scaling exhausted.
//   r9: XCD swizzle: 16 same-line readers/XCD (enc1) = -10us WIN;
//       64 readers/XCD (dec3) = +27us LOSS (L2 same-address port storm).
//       Reader-count per line is the controlling variable.
//   r10: dec3 D=4 dbuf: 579us best. dec3 time INVARIANT ~87us while traffic
//        halved -> not BW-bound; the winning lever is L2-locality with FEW
//        same-line readers.
//   => r11: dec3 gets 16-reader-group swizzle (the enc1-winning config):
//      group=(b,xb) 512KB slab, 16 yb-blocks/group on one XCD (2MB/XCD
//      resident). Plus attn_channel (only 64 blocks!) PV-phase split 4-way.
#define PIPE_FENCE() asm volatile("" ::: "memory")

// ===========================================================================
// Generic big-P 1x1 conv, 1D grid, depth-D double-buffered fenced pipeline.
// swz=0 natural; swz=1 z-stripe (enc1: 2 z per XCD, 16 readers/line);
// swz=2 (b,xb)-group stripe (dec3: 16 yb-blocks of one 512KB slab per XCD).
//   enc1: OT=8  D=8, nx=4 ny=4,  256 blocks, swz=1.
//   dec3: OT=16 D=4, nx=4 ny=16, 512 blocks, swz=2.
// ===========================================================================
template<int OT, int D, bool HASBN, bool HASSTATS>
__global__ __launch_bounds__(256,2) void conv1x1_kernel(
    const float* __restrict__ in0, const float* __restrict__ in1,
    const float* __restrict__ w, float* __restrict__ out,
    const float* __restrict__ stIn, float* __restrict__ stOut,
    int I, int O, int P, int wio, int zsplit, float invN,
    int nx, int ny, int swz)
{
  __shared__ float wl[2048];
  __shared__ float bnm[256], bnr[256];
  int tid = threadIdx.x;

  int bid = blockIdx.x;
  int nb  = nx*ny;          // blocks per z
  int xb, yb, z;
  if(swz == 1){
    int xcd = bid & 7, slot = bid >> 3;
    int zl = slot/nb, inner = slot - zl*nb;
    xb = inner % nx; yb = inner / nx; z = xcd + 8*zl;
  } else if(swz == 2){
    // group g=(z*nx+xb) pinned to XCD g&7; 16 yb-members contiguous slots.
    int xcd = bid & 7, slot = bid >> 3;
    int gq = slot / ny, m = slot - gq*ny;
    int g  = xcd + 8*gq;
    xb = g % nx; z = g / nx; yb = m;
  } else {
    int zq = bid / nb, inner = bid - zq*nb;
    xb = inner % nx; yb = inner / nx; z = zq;
  }

  int o0 = yb*OT;
  int t  = (z >= zsplit) ? 1 : 0;
  int b  = t ? (z - zsplit) : z;
  const float* in = t ? in1 : in0;

  for(int idx=tid; idx<I*OT; idx+=256){
    int i = idx/OT, j = idx - i*OT;
    wl[idx] = wio ? w[(size_t)i*O + o0 + j] : w[(size_t)(o0+j)*I + i];
  }
  if(HASBN){
    for(int i=tid; i<I; i+=256){
      float s  = stIn[((size_t)t*I + i)*2];
      float s2 = stIn[((size_t)t*I + i)*2+1];
      float m  = s*invN;
      bnm[i] = m;
      bnr[i] = rsqrtf(s2*invN - m*m + EPS_BN);
    }
  }
  __syncthreads();

  int p4 = xb*256 + tid;
  const float4* inb = (const float4*)(in + (size_t)b*I*P) + p4;
  int P4 = P >> 2;

  float acc[OT][4];
#pragma unroll
  for(int j=0;j<OT;j++){ acc[j][0]=acc[j][1]=acc[j][2]=acc[j][3]=0.f; }

  auto consume = [&](const float4* vv, int i0){
#pragma unroll
    for(int u=0;u<D;u++){
      float4 v = vv[u];
      if(HASBN){
        float m = bnm[i0+u], r = bnr[i0+u];
        v.x = fmaxf((v.x-m)*r, 0.f); v.y = fmaxf((v.y-m)*r, 0.f);
        v.z = fmaxf((v.z-m)*r, 0.f); v.w = fmaxf((v.w-m)*r, 0.f);
      }
      const float* wr = &wl[(i0+u)*OT];
#pragma unroll
      for(int j=0;j<OT;j++){
        float wv = wr[j];
        acc[j][0] = fmaf(wv, v.x, acc[j][0]);
        acc[j][1] = fmaf(wv, v.y, acc[j][1]);
        acc[j][2] = fmaf(wv, v.z, acc[j][2]);
        acc[j][3] = fmaf(wv, v.w, acc[j][3]);
      }
    }
  };

  float4 va[D], vb[D];
#pragma unroll
  for(int u=0;u<D;u++) va[u] = inb[(size_t)u*P4];
  PIPE_FENCE();

  for(int i0=0;i0<I;i0+=2*D){
#pragma unroll
    for(int u=0;u<D;u++) vb[u] = inb[(size_t)(i0+D+u)*P4];
    PIPE_FENCE();
    consume(va, i0);
    if(i0+2*D < I){
#pragma unroll
      for(int u=0;u<D;u++) va[u] = inb[(size_t)(i0+2*D+u)*P4];
    }
    PIPE_FENCE();
    consume(vb, i0+D);
  }

  float4* ob = (float4*)(out + ((size_t)z*O + o0)*P) + p4;
#pragma unroll
  for(int j=0;j<OT;j++){
    float4 vv = {acc[j][0], acc[j][1], acc[j][2], acc[j][3]};
    ob[(size_t)j*P4] = vv;
  }

  if(HASSTATS){
#pragma unroll
    for(int j=0;j<OT;j++){
      float s  = acc[j][0]+acc[j][1]+acc[j][2]+acc[j][3];
      float s2 = acc[j][0]*acc[j][0]+acc[j][1]*acc[j][1]
               + acc[j][2]*acc[j][2]+acc[j][3]*acc[j][3];
      for(int off=32; off>0; off>>=1){
        s  += __shfl_down(s,  off, 64);
        s2 += __shfl_down(s2, off, 64);
      }
      if((tid & 63)==0){
        atomicAdd(&stOut[((size_t)t*O + o0 + j)*2],   s);
        atomicAdd(&stOut[((size_t)t*O + o0 + j)*2+1], s2);
      }
    }
  }
}

// ===========================================================================
// Small-P (P=1024) 1x1 conv: 128 f4-cols x 2 o-slices. 8-deep pipeline.
// ===========================================================================
template<int OT, bool HASBN, bool HASSTATS>
__global__ __launch_bounds__(256) void conv1x1_small(
    const float* __restrict__ in0, const float* __restrict__ in1,
    const float* __restrict__ w, float* __restrict__ out,
    const float* __restrict__ stIn, float* __restrict__ stOut,
    int I, int O, int wio, int zsplit, float invN)
{
  __shared__ float wl[512];
  __shared__ float bnm[128], bnr[128];
  int tid = threadIdx.x;
  int z  = blockIdx.z;
  int t  = (z >= zsplit) ? 1 : 0;
  int b  = t ? (z - zsplit) : z;
  const float* in = t ? in1 : in0;
  int W2 = 2*OT;

  for(int idx=tid; idx<I*W2; idx+=256){
    int i = idx/W2, slot = idx - i*W2;
    int oabs = blockIdx.y*W2 + slot;
    wl[idx] = wio ? w[(size_t)i*O + oabs] : w[(size_t)oabs*I + i];
  }
  if(HASBN){
    for(int i=tid; i<I; i+=256){
      float s  = stIn[((size_t)t*I + i)*2];
      float s2 = stIn[((size_t)t*I + i)*2+1];
      float m  = s*invN;
      bnm[i] = m;
      bnr[i] = rsqrtf(s2*invN - m*m + EPS_BN);
    }
  }
  __syncthreads();

  int p4 = blockIdx.x*128 + (tid & 127);
  int os = tid >> 7;
  const float4* inb = (const float4*)(in + (size_t)b*I*1024) + p4;

  float acc[OT][4];
#pragma unroll
  for(int j=0;j<OT;j++){ acc[j][0]=acc[j][1]=acc[j][2]=acc[j][3]=0.f; }

  float4 vb[8];
  for(int i0=0;i0<I;i0+=8){
#pragma unroll
    for(int u=0;u<8;u++) vb[u] = inb[(size_t)(i0+u)*256];
    PIPE_FENCE();
#pragma unroll
    for(int u=0;u<8;u++){
      float4 v = vb[u];
      if(HASBN){
        float m = bnm[i0+u], r = bnr[i0+u];
        v.x = fmaxf((v.x-m)*r, 0.f); v.y = fmaxf((v.y-m)*r, 0.f);
        v.z = fmaxf((v.z-m)*r, 0.f); v.w = fmaxf((v.w-m)*r, 0.f);
      }
      const float* wr = &wl[(i0+u)*W2 + os*OT];
#pragma unroll
      for(int j=0;j<OT;j++){
        float wv = wr[j];
        acc[j][0] = fmaf(wv, v.x, acc[j][0]);
        acc[j][1] = fmaf(wv, v.y, acc[j][1]);
        acc[j][2] = fmaf(wv, v.z, acc[j][2]);
        acc[j][3] = fmaf(wv, v.w, acc[j][3]);
      }
    }
  }

  int obase = blockIdx.y*W2 + os*OT;
  float4* ob = (float4*)(out + ((size_t)z*O + obase)*1024) + p4;
#pragma unroll
  for(int j=0;j<OT;j++){
    float4 vv = {acc[j][0], acc[j][1], acc[j][2], acc[j][3]};
    ob[(size_t)j*256] = vv;
  }

  if(HASSTATS){
#pragma unroll
    for(int j=0;j<OT;j++){
      float s  = acc[j][0]+acc[j][1]+acc[j][2]+acc[j][3];
      float s2 = acc[j][0]*acc[j][0]+acc[j][1]*acc[j][1]
               + acc[j][2]*acc[j][2]+acc[j][3]*acc[j][3];
      for(int off=32; off>0; off>>=1){
        s  += __shfl_down(s,  off, 64);
        s2 += __shfl_down(s2, off, 64);
      }
      if((tid & 63)==0){
        atomicAdd(&stOut[((size_t)t*O + obase + j)*2],   s);
        atomicAdd(&stOut[((size_t)t*O + obase + j)*2+1], s2);
      }
    }
  }
}

// ===========================================================================
// Encoder k=2 s=2 conv (unchanged)
// ===========================================================================
__global__ __launch_bounds__(256) void conv2x2s2_bn_kernel(
    const float* __restrict__ in, const float* __restrict__ w,
    float* __restrict__ out, const float* __restrict__ stIn,
    float* __restrict__ stOut, float invN)
{
  __shared__ float wl[512];
  __shared__ float bnm[32], bnr[32];
  int tid = threadIdx.x;
  int o0 = blockIdx.x*4;
  int rq = blockIdx.y;
  int z  = blockIdx.z;
  int t  = z >> 3;

  for(int idx=tid; idx<512; idx+=256){
    int osub = idx>>7, ch=(idx>>2)&31, pq=idx&3;
    wl[idx] = w[(((size_t)(o0+osub)*32 + ch)*4) + pq];
  }
  if(tid < 32){
    float s  = stIn[((size_t)t*32 + tid)*2];
    float s2 = stIn[((size_t)t*32 + tid)*2+1];
    float m  = s*invN;
    bnm[tid] = m;
    bnr[tid] = rsqrtf(s2*invN - m*m + EPS_BN);
  }
  __syncthreads();

  int os   = tid >> 6;
  int slot = tid & 63;
  int h    = rq*8 + (slot>>3);
  int wg   = slot & 7;
  int cb   = wg*8;
  const float* wbase = &wl[os*128];
  const float* inz = in + (size_t)z*32*4096;

  float acc[4] = {0,0,0,0};
  float4 c0,c1,c2,c3, n0_,n1_,n2_,n3_;
  c0 = *(const float4*)(inz + (size_t)0*4096 + (2*h)*64 + cb);
  c1 = *(const float4*)(inz + (size_t)0*4096 + (2*h)*64 + cb + 4);
  c2 = *(const float4*)(inz + (size_t)0*4096 + (2*h+1)*64 + cb);
  c3 = *(const float4*)(inz + (size_t)0*4096 + (2*h+1)*64 + cb + 4);
  for(int ch=0; ch<32; ch++){
    if(ch < 31){
      n0_ = *(const float4*)(inz + (size_t)(ch+1)*4096 + (2*h)*64 + cb);
      n1_ = *(const float4*)(inz + (size_t)(ch+1)*4096 + (2*h)*64 + cb + 4);
      n2_ = *(const float4*)(inz + (size_t)(ch+1)*4096 + (2*h+1)*64 + cb);
      n3_ = *(const float4*)(inz + (size_t)(ch+1)*4096 + (2*h+1)*64 + cb + 4);
    }
    float m = bnm[ch], r = bnr[ch];
    float t0[8] = {c0.x,c0.y,c0.z,c0.w,c1.x,c1.y,c1.z,c1.w};
    float t1[8] = {c2.x,c2.y,c2.z,c2.w,c3.x,c3.y,c3.z,c3.w};
#pragma unroll
    for(int e=0;e<8;e++){
      t0[e] = fmaxf((t0[e]-m)*r, 0.f);
      t1[e] = fmaxf((t1[e]-m)*r, 0.f);
    }
    const float* wp = wbase + ch*4;
#pragma unroll
    for(int k=0;k<4;k++){
      acc[k] = fmaf(wp[0], t0[2*k],   acc[k]);
      acc[k] = fmaf(wp[1], t0[2*k+1], acc[k]);
      acc[k] = fmaf(wp[2], t1[2*k],   acc[k]);
      acc[k] = fmaf(wp[3], t1[2*k+1], acc[k]);
    }
    c0=n0_; c1=n1_; c2=n2_; c3=n3_;
  }

  float4 vv = {acc[0],acc[1],acc[2],acc[3]};
  *(float4*)(out + ((size_t)z*32 + o0+os)*1024 + h*32 + wg*4) = vv;

  float s  = acc[0]+acc[1]+acc[2]+acc[3];
  float s2 = acc[0]*acc[0]+acc[1]*acc[1]+acc[2]*acc[2]+acc[3]*acc[3];
  for(int off=32; off>0; off>>=1){
    s  += __shfl_down(s,  off, 64);
    s2 += __shfl_down(s2, off, 64);
  }
  if((tid & 63)==0){
    atomicAdd(&stOut[((size_t)t*32 + o0 + os)*2],   s);
    atomicAdd(&stOut[((size_t)t*32 + o0 + os)*2+1], s2);
  }
}

// ===========================================================================
// ConvTranspose k=2 s=2 (pipeline fence)
// ===========================================================================
__global__ __launch_bounds__(256) void upsample2x2_bn_kernel(
    const float* __restrict__ in, const float* __restrict__ w,
    float* __restrict__ out, const float* __restrict__ stIn,
    float* __restrict__ stOut, float invN)
{
  __shared__ float wl[1024];
  __shared__ float bnm[128], bnr[128];
  int tid = threadIdx.x;
  int o0 = blockIdx.x*2;
  int b  = blockIdx.y;

  for(int idx=tid; idx<1024; idx+=256){
    int pq = idx & 3, r = idx >> 2;
    int i = r >> 1, j = r & 1;
    wl[idx] = w[((size_t)i*128 + o0+j)*4 + pq];
  }
  if(tid < 128){
    float s  = stIn[(size_t)tid*2];
    float s2 = stIn[(size_t)tid*2+1];
    float m  = s*invN;
    bnm[tid] = m;
    bnr[tid] = rsqrtf(s2*invN - m*m + EPS_BN);
  }
  __syncthreads();

  int h  = tid >> 3;
  int wg = tid & 7;
  int w0 = wg*4;

  float acc[2][16];
#pragma unroll
  for(int j=0;j<2;j++) for(int e=0;e<16;e++) acc[j][e]=0.f;

  float4 vb4[8];
  for(int i0=0;i0<128;i0+=8){
#pragma unroll
    for(int u=0;u<8;u++)
      vb4[u] = *(const float4*)(in + (((size_t)b*128+i0+u)*1024) + h*32 + w0);
    PIPE_FENCE();
#pragma unroll
    for(int u=0;u<8;u++){
      int i = i0+u;
      float4 v = vb4[u];
      float m = bnm[i], r = bnr[i];
      float vk[4] = {fmaxf((v.x-m)*r,0.f), fmaxf((v.y-m)*r,0.f),
                     fmaxf((v.z-m)*r,0.f), fmaxf((v.w-m)*r,0.f)};
#pragma unroll
      for(int j=0;j<2;j++){
        const float* wj = &wl[(i*2+j)*4];
#pragma unroll
        for(int pq=0;pq<4;pq++){
#pragma unroll
          for(int k=0;k<4;k++)
            acc[j][pq*4+k] = fmaf(wj[pq], vk[k], acc[j][pq*4+k]);
        }
      }
    }
  }

#pragma unroll
  for(int j=0;j<2;j++){
    float* ob = out + ((size_t)b*128 + o0+j)*4096;
#pragma unroll
    for(int p=0;p<2;p++){
      float4 A = {acc[j][(p*2+0)*4+0], acc[j][(p*2+1)*4+0],
                  acc[j][(p*2+0)*4+1], acc[j][(p*2+1)*4+1]};
      float4 B = {acc[j][(p*2+0)*4+2], acc[j][(p*2+1)*4+2],
                  acc[j][(p*2+0)*4+3], acc[j][(p*2+1)*4+3]};
      *(float4*)(ob + (2*h+p)*64 + 2*w0)     = A;
      *(float4*)(ob + (2*h+p)*64 + 2*w0 + 4) = B;
    }
  }

#pragma unroll
  for(int j=0;j<2;j++){
    float s=0.f, s2=0.f;
#pragma unroll
    for(int e=0;e<16;e++){ s += acc[j][e]; s2 += acc[j][e]*acc[j][e]; }
    for(int off=32; off>0; off>>=1){
      s  += __shfl_down(s,  off, 64);
      s2 += __shfl_down(s2, off, 64);
    }
    if((tid & 63)==0){
      atomicAdd(&stOut[((size_t)(o0+j))*2],   s);
      atomicAdd(&stOut[((size_t)(o0+j))*2+1], s2);
    }
  }
}

// ===========================================================================
__global__ __launch_bounds__(256) void bn_final_kernel(
    float* __restrict__ x, const float* __restrict__ st, float invN)
{
  int idx4 = blockIdx.x*256 + threadIdx.x;
  int c = (idx4 >> 10) & 255;
  float s  = st[(size_t)c*2];
  float s2 = st[(size_t)c*2+1];
  float m  = s*invN;
  float r  = rsqrtf(s2*invN - m*m + EPS_BN);
  float4 v = ((float4*)x)[idx4];
  v.x = fmaxf((v.x-m)*r, 0.f); v.y = fmaxf((v.y-m)*r, 0.f);
  v.z = fmaxf((v.z-m)*r, 0.f); v.w = fmaxf((v.w-m)*r, 0.f);
  ((float4*)x)[idx4] = v;
}

// ===========================================================================
// depthwise 3x3, pad 1, f4 per thread, whole 32x32 per (c,b). grid (C,B).
// ===========================================================================
__global__ __launch_bounds__(256) void dwconv3x3_kernel(
    const float* __restrict__ in, const float* __restrict__ w,
    float* __restrict__ out, int C)
{
  int c = blockIdx.x, b = blockIdx.y;
  int tid = threadIdx.x;
  __shared__ float wl[9];
  if(tid < 9) wl[tid] = w[c*9 + tid];
  __syncthreads();
  int h = tid >> 3, x4 = tid & 7;
  int c0 = x4*4;
  const float* base = in + ((size_t)b*C + c)*1024;
  float ax=0.f, ay=0.f, az=0.f, aw=0.f;
#pragma unroll
  for(int dr=0; dr<3; dr++){
    int r = h + dr - 1;
    if((unsigned)r >= 32u) continue;
    const float* row = base + r*32 + c0;
    float4 cc = *(const float4*)row;
    float l  = (x4>0) ? row[-1] : 0.f;
    float rr = (x4<7) ? row[4]  : 0.f;
    float w0=wl[dr*3], w1=wl[dr*3+1], w2=wl[dr*3+2];
    ax = fmaf(w0,l,   fmaf(w1,cc.x, fmaf(w2,cc.y, ax)));
    ay = fmaf(w0,cc.x,fmaf(w1,cc.y, fmaf(w2,cc.z, ay)));
    az = fmaf(w0,cc.y,fmaf(w1,cc.z, fmaf(w2,cc.w, az)));
    aw = fmaf(w0,cc.z,fmaf(w1,cc.w, fmaf(w2,rr,  aw)));
  }
  float4 vv = {ax,ay,az,aw};
  *(float4*)(out + ((size_t)b*C + c)*1024 + h*32 + c0) = vv;
}

// ===========================================================================
// full 3x3 conv, pad 1, f4 per thread, whole 32x32 per (o,b). grid (O,B).
// ===========================================================================
__global__ __launch_bounds__(256) void conv3x3_kernel(
    const float* __restrict__ in, const float* __restrict__ w,
    float* __restrict__ out, int IC)
{
  int o = blockIdx.x, b = blockIdx.y;
  int tid = threadIdx.x;
  __shared__ float wl[576];
  for(int t=tid; t<IC*9; t+=256) wl[t] = w[(size_t)o*IC*9 + t];
  __syncthreads();
  int h = tid >> 3, x4 = tid & 7;
  int c0 = x4*4;
  const float* inb = in + (size_t)b*IC*1024;
  float ax=0.f, ay=0.f, az=0.f, aw=0.f;
#pragma unroll 2
  for(int i=0;i<IC;i++){
    const float* base = inb + (size_t)i*1024;
    const float* wp = &wl[i*9];
#pragma unroll
    for(int dr=0; dr<3; dr++){
      int r = h + dr - 1;
      if((unsigned)r >= 32u) continue;
      const float* row = base + r*32 + c0;
      float4 cc = *(const float4*)row;
      float l  = (x4>0) ? row[-1] : 0.f;
      float rr = (x4<7) ? row[4]  : 0.f;
      float w0=wp[dr*3], w1=wp[dr*3+1], w2=wp[dr*3+2];
      ax = fmaf(w0,l,   fmaf(w1,cc.x, fmaf(w2,cc.y, ax)));
      ay = fmaf(w0,cc.x,fmaf(w1,cc.y, fmaf(w2,cc.z, ay)));
      az = fmaf(w0,cc.y,fmaf(w1,cc.z, fmaf(w2,cc.w, az)));
      aw = fmaf(w0,cc.z,fmaf(w1,cc.w, fmaf(w2,rr,  aw)));
    }
  }
  float4 vv = {ax,ay,az,aw};
  *(float4*)(out + ((size_t)b*gridDim.x + o)*1024 + h*32 + c0) = vv;
}

// ===========================================================================
// Row norms only: scl[r] = 1/max(||row||,1e-12). r<512: q rows; else k rows.
// ===========================================================================
__global__ __launch_bounds__(256) void norm_scale_kernel(
    const float* __restrict__ q, const float* __restrict__ kv,
    float* __restrict__ scl)
{
  int r = blockIdx.x;
  const float* p;
  if(r < 512){ int b=r>>6, c=r&63; p = q + ((size_t)b*64+c)*1024; }
  else { int rr=r-512; int b=rr>>6, c=rr&63; p = kv + ((size_t)b*128+c)*1024; }
  int tid = threadIdx.x;
  float4 v = ((const float4*)p)[tid];
  float s = v.x*v.x + v.y*v.y + v.z*v.z + v.w*v.w;
  __shared__ float ls[256];
  ls[tid]=s; __syncthreads();
  for(int st=128; st>0; st>>=1){ if(tid<st) ls[tid]+=ls[tid+st]; __syncthreads(); }
  if(tid==0) scl[r] = 1.f/fmaxf(sqrtf(ls[0]), 1e-12f);
}

// ===========================================================================
// Spatial attention pass 1 (norm scales applied on load). grid (16,8,8).
// ===========================================================================
__global__ __launch_bounds__(256) void attn_pass1(
    const float* __restrict__ q, const float* __restrict__ kv,
    const float* __restrict__ temp, const float* __restrict__ scl,
    float* __restrict__ den_out)
{
  int bx = blockIdx.x, hh = blockIdx.y, b = blockIdx.z;
  int nchunk = bx >> 2, mq = bx & 3;
  int tid = threadIdx.x;
  __shared__ __align__(16) float kl[256*12];
  const float* kb = kv + ((size_t)b*128 + hh*8)*1024 + mq*256;
  for(int t=tid;t<2048;t+=256){
    int c=t>>8, m=t&255;
    kl[m*12+c] = kb[(size_t)c*1024+m] * scl[512 + b*64 + hh*8 + c];
  }
  __syncthreads();
  int n = nchunk*256 + tid;
  const float* qp = q + ((size_t)b*64 + hh*8)*1024 + n;
  float th = temp[hh];
  float mxb = fabsf(th);
  float qr[8];
#pragma unroll
  for(int c=0;c<8;c++) qr[c] = qp[(size_t)c*1024] * scl[b*64+hh*8+c] * th;
  const float4* kl4 = (const float4*)kl;
  float den = 0.f, den2 = 0.f;
  for(int m=0;m<256;m+=2){
    float4 a  = kl4[m*3],     a2 = kl4[m*3+1];
    float4 bt = kl4[(m+1)*3], b2 = kl4[(m+1)*3+1];
    float s0 = qr[0]*a.x+qr[1]*a.y+qr[2]*a.z+qr[3]*a.w
             + qr[4]*a2.x+qr[5]*a2.y+qr[6]*a2.z+qr[7]*a2.w;
    float s1 = qr[0]*bt.x+qr[1]*bt.y+qr[2]*bt.z+qr[3]*bt.w
             + qr[4]*b2.x+qr[5]*b2.y+qr[6]*b2.z+qr[7]*b2.w;
    den  += __expf(s0 - mxb);
    den2 += __expf(s1 - mxb);
  }
  atomicAdd(&den_out[((size_t)(b*8+hh))*1024+n], den+den2);
}

// ===========================================================================
// Spatial attention pass 2 (norm scales applied on load). grid (16,8,8).
// ===========================================================================
__global__ __launch_bounds__(256) void attn_pass2(
    const float* __restrict__ q, const float* __restrict__ kv,
    const float* __restrict__ temp, const float* __restrict__ scl,
    const float* __restrict__ den, float* __restrict__ out)
{
  int bx = blockIdx.x, hh = blockIdx.y, b = blockIdx.z;
  int mchunk = bx >> 2, nq = bx & 3;
  int tid = threadIdx.x;
  __shared__ __align__(16) float ql[256*12];
  __shared__ __align__(16) float vl[256*12];
  __shared__ float idl[256];
  int bh = b*8+hh;
  int n0 = nq*256;
  const float* qb = q  + ((size_t)b*64 + hh*8)*1024 + n0;
  const float* vb = kv + ((size_t)b*128 + 64 + hh*8)*1024 + n0;
  for(int t=tid;t<2048;t+=256){
    int c=t>>8, n=t&255;
    ql[n*12+c] = qb[(size_t)c*1024+n] * scl[b*64+hh*8+c];
    vl[n*12+c] = vb[(size_t)c*1024+n];
  }
  idl[tid] = 1.f/den[(size_t)bh*1024 + n0 + tid];
  __syncthreads();
  int m = mchunk*256 + tid;
  const float* kb = kv + ((size_t)b*128 + hh*8)*1024 + m;
  float th = temp[hh];
  float mxb = fabsf(th);
  float kr[8];
#pragma unroll
  for(int c=0;c<8;c++) kr[c] = kb[(size_t)c*1024] * scl[512+b*64+hh*8+c] * th;
  float acc[8] = {0,0,0,0,0,0,0,0};
  const float4* ql4 = (const float4*)ql;
  const float4* vl4 = (const float4*)vl;
  for(int n=0;n<256;n+=2){
    float4 qa = ql4[n*3],     qa2 = ql4[n*3+1];
    float4 qc = ql4[(n+1)*3], qc2 = ql4[(n+1)*3+1];
    float s0 = kr[0]*qa.x+kr[1]*qa.y+kr[2]*qa.z+kr[3]*qa.w
             + kr[4]*qa2.x+kr[5]*qa2.y+kr[6]*qa2.z+kr[7]*qa2.w;
    float s1 = kr[0]*qc.x+kr[1]*qc.y+kr[2]*qc.z+kr[3]*qc.w
             + kr[4]*qc2.x+kr[5]*qc2.y+kr[6]*qc2.z+kr[7]*qc2.w;
    float p0 = __expf(s0 - mxb) * idl[n];
    float p1 = __expf(s1 - mxb) * idl[n+1];
    float4 va = vl4[n*3],     va2 = vl4[n*3+1];
    float4 vc = vl4[(n+1)*3], vc2 = vl4[(n+1)*3+1];
    acc[0]+=p0*va.x + p1*vc.x; acc[1]+=p0*va.y + p1*vc.y;
    acc[2]+=p0*va.z + p1*vc.z; acc[3]+=p0*va.w + p1*vc.w;
    acc[4]+=p0*va2.x + p1*vc2.x; acc[5]+=p0*va2.y + p1*vc2.y;
    acc[6]+=p0*va2.z + p1*vc2.z; acc[7]+=p0*va2.w + p1*vc2.w;
  }
  float* ob = out + ((size_t)b*64 + hh*8)*1024 + m;
#pragma unroll
  for(int c=0;c<8;c++) atomicAdd(&ob[(size_t)c*1024], acc[c]);
}

// ===========================================================================
// Channel attention; gram scaled by qs[c]*ks[d]*t post-reduction.
// grid (8,8,4): nq = n-quarter. Gram recomputed per quarter (cheap);
// PV/output phase 4x parallel (was only 64 blocks total -> 256).
// ===========================================================================
__global__ __launch_bounds__(256) void attn_channel(
    const float* __restrict__ q, const float* __restrict__ kv,
    const float* __restrict__ temp, const float* __restrict__ scl,
    float* out)
{
  int hh = blockIdx.x, b = blockIdx.y, nq = blockIdx.z;
  __shared__ float kl[8192];
  const float* qb = q  + ((size_t)b*64 + hh*8)*1024;
  const float* kb = kv + ((size_t)b*128 + hh*8)*1024;
  const float* vb = kv + ((size_t)b*128 + 64 + hh*8)*1024;
  int tid = threadIdx.x;
  for(int t=tid;t<8192;t+=256) kl[t]=kb[t];
  __syncthreads();
  __shared__ float part[256];
  __shared__ float a[64];
  {
    int pair = tid >> 2, seg = tid & 3;
    int c = pair >> 3, d = pair & 7;
    const float* qrow = qb + (size_t)c*1024 + seg*256;
    const float* krow = kl + d*1024 + seg*256;
    float s = 0.f;
#pragma unroll 4
    for(int n=0;n<256;n++) s += qrow[n]*krow[n];
    part[tid] = s;
  }
  __syncthreads();
  if(tid < 64){
    int c = tid >> 3, d = tid & 7;
    float g = part[tid*4]+part[tid*4+1]+part[tid*4+2]+part[tid*4+3];
    part[tid] = g * scl[b*64+hh*8+c] * scl[512+b*64+hh*8+d] * temp[hh];
  }
  __syncthreads();
  if(tid < 8){
    float mx = -3.4e38f;
    for(int d=0;d<8;d++) mx = fmaxf(mx, part[tid*8+d]);
    float den = 0.f;
    float e[8];
    for(int d=0;d<8;d++){ e[d] = __expf(part[tid*8+d]-mx); den+=e[d]; }
    float inv = 1.f/den;
    for(int d=0;d<8;d++) a[tid*8+d] = e[d]*inv;
  }
  __syncthreads();
  float* ob = out + ((size_t)b*64 + hh*8)*1024;
  {
    int n = nq*256 + tid;     // this block's n-quarter; one writer per (c,n)
    float vv[8];
#pragma unroll
    for(int d=0;d<8;d++) vv[d] = vb[(size_t)d*1024+n];
#pragma unroll
    for(int c=0;c<8;c++){
      float s = 0.f;
#pragma unroll
      for(int d=0;d<8;d++) s += a[c*8+d]*vv[d];
      ob[(size_t)c*1024+n] += s;
    }
  }
}

// ===========================================================================
extern "C" void kernel_launch(void* const* d_in, const int* in_sizes, int n_in,
                              void* d_out, int out_size, void* d_ws, size_t ws_size,
                              hipStream_t stream)
{
  (void)in_sizes; (void)n_in; (void)out_size; (void)ws_size;
  const float* x      = (const float*)d_in[0];
  const float* y      = (const float*)d_in[1];
  const float* temp   = (const float*)d_in[2];
  const float* enc_w1 = (const float*)d_in[3];
  const float* enc_w2 = (const float*)d_in[4];
  const float* enc_w3 = (const float*)d_in[5];
  const float* kv_w   = (const float*)d_in[6];
  const float* kv_dw_w= (const float*)d_in[7];
  const float* q_w    = (const float*)d_in[8];
  const float* q_dw_w = (const float*)d_in[9];
  const float* proj_w = (const float*)d_in[10];
  const float* dec_w1 = (const float*)d_in[11];
  const float* dec_w2 = (const float*)d_in[12];
  const float* dec_w3 = (const float*)d_in[13];
  float* out = (float*)d_out;

  float* W   = (float*)d_ws;
  float* ST  = W;                    // 2048
  float* ST0 = ST;
  float* ST1 = ST + 128;
  float* ST2 = ST + 256;
  float* ST3 = ST + 512;
  float* ST4 = ST + 768;
  float* ST5 = ST + 1024;
  float* A    = W + 2048;            // 2,097,152-float region, multiply reused
  float* E1   = A;
  float* KV1  = A;
  float* QPre = A + 1048576;
  float* ATTN = A;
  float* PROJ = A + 524288;
  float* D1   = A + 1048576;
  float* E2   = W + 2099200;         //   524,288
  float* E3   = W + 2623488;         // 1,048,576
  float* KV   = W + 3672064;         // 1,048,576
  float* Q    = W + 4720640;         //   524,288
  float* SCL  = W + 5244928;         //     1,024 (q/k reciprocal norms)
  float* DEN  = W + 5245952;         //    65,536
  float* D2   = W + 2099200;         // 4,194,304 (overlaps E2..DEN, dead then)

  const float inv32k = 1.f/32768.f, inv8k = 1.f/8192.f;

  hipMemsetAsync(ST, 0, 2048*sizeof(float), stream);
  hipMemsetAsync(DEN, 0, 65536*sizeof(float), stream);

  // ---- encoder ----
  // enc1: OT=8 D=8 dbuf, z-stripe swizzle (r9 win: 16 readers/line).
  conv1x1_kernel<8,8,false,true><<<256,256,0,stream>>>(
      x, y, enc_w1, E1, nullptr, ST0, 256, 32, 4096, 0, 8, 0.f,
      /*nx=*/4, /*ny=*/4, /*swz=*/1);
  conv2x2s2_bn_kernel<<<dim3(8,4,16),256,0,stream>>>(E1, enc_w2, E2, ST0, ST1, inv32k);
  conv1x1_small<1,true,true><<<dim3(2,32,16),256,0,stream>>>(
      E2, E2 + (size_t)8*32*1024, enc_w3, E3, ST1, ST2, 32, 64, 0, 8, inv8k);

  // ---- kv = dw3x3(1x1(x_enc)); q = conv3x3(1x1(y_enc)) ----
  conv1x1_small<1,true,false><<<dim3(2,64,8),256,0,stream>>>(
      E3, E3, kv_w, KV1, ST2, nullptr, 64, 128, 0, 999, inv8k);
  dwconv3x3_kernel<<<dim3(128,8),256,0,stream>>>(KV1, kv_dw_w, KV, 128);
  conv1x1_small<1,true,false><<<dim3(2,32,8),256,0,stream>>>(
      E3 + (size_t)8*64*1024, E3, q_w, QPre, ST2 + 128, nullptr, 64, 64, 0, 999, inv8k);
  conv3x3_kernel<<<dim3(64,8),256,0,stream>>>(QPre, q_dw_w, Q, 64);

  // ATTN region (overlapping KV1/QPre) dead now — zero for atomics
  hipMemsetAsync(ATTN, 0, 524288*sizeof(float), stream);

  // ---- q/k row norms (scales only; tensors stay raw) ----
  norm_scale_kernel<<<1024,256,0,stream>>>(Q, KV, SCL);

  // ---- attention ----
  attn_pass1<<<dim3(16,8,8),256,0,stream>>>(Q, KV, temp, SCL, DEN);
  attn_pass2<<<dim3(16,8,8),256,0,stream>>>(Q, KV, temp, SCL, DEN, ATTN);
  attn_channel<<<dim3(8,8,4),256,0,stream>>>(Q, KV, temp, SCL, ATTN);

  // ---- proj ----
  conv1x1_small<1,false,false><<<dim3(2,32,8),256,0,stream>>>(
      ATTN, ATTN, proj_w, PROJ, nullptr, nullptr, 64, 64, 0, 999, 0.f);

  // ---- decoder ----
  conv1x1_small<1,false,true><<<dim3(2,64,8),256,0,stream>>>(
      PROJ, PROJ, dec_w1, D1, nullptr, ST3, 64, 128, 1, 999, 0.f);
  upsample2x2_bn_kernel<<<dim3(64,8),256,0,stream>>>(D1, dec_w2, D2, ST3, ST4, inv8k);
  // dec3: OT=16 D=4 dbuf, 16-reader GROUP swizzle: the 16 yb-blocks of each
  // (b,xb) 512KB slab share one XCD (2MB resident/XCD < 4MB L2; 16
  // readers/line = the enc1-proven count, not r9's failed 64).
  conv1x1_kernel<16,4,true,true><<<512,256,0,stream>>>(
      D2, D2, dec_w3, out, ST4, ST5, 128, 256, 4096, 1, 999, inv32k,
      /*nx=*/4, /*ny=*/16, /*swz=*/2);
  bn_final_kernel<<<8192,256,0,stream>>>(out, ST5, inv32k);
}

// Round 12
// 575.675 us; speedup vs baseline: 1.0126x; 1.0126x over previous
//
#include <hip/hip_runtime.h>
#include <hip/hip_bf16.h>

#define EPS_BN 1e-5f

// Pipeline fence.
// HISTORY (do not regress):
//   r1: no fence                      -> compiler sinks loads, pipeline gone.
//   r2: asm("" ::: "memory") + (256,2)-> VGPR 128, loads stay batched... BUT
//   r11 diagnosis: the "memory" clobber makes SIInsertWaitcnts emit
//       s_waitcnt vmcnt(0) lgkmcnt(0) BEFORE EVERY FENCE -> each iteration
//       drains the just-issued prefetch. Evidence: VALUBusy 11%, GEMM time
//       invariant (82-88us) across traffic x2-x8, dbuf depth, occupancy;
//       r10 D=4 vs D=8 neutral. The fence WAS the serializer.
//   => r12: __builtin_amdgcn_sched_barrier(0): compile-time-only scheduling
//      pin (keeps load batching / regalloc) with NO waitcnt semantics —
//      hardware waits only on registers actually consumed; prefetch stays
//      in flight.
//   r3: (256,4) -> allocator rounds to 64 VGPR, 1GB spill. Never.
//   r6: __shfl bulk dedup = ds_bpermute crossbar storm. Never.
//   r7: column-per-thread OS=64 -> spill. Never.
//   r9/r11: XCD swizzle with <=16 same-line readers/XCD = win (enc1 z-stripe,
//       dec3 (b,xb)-group); 64 readers/XCD = L2 port storm. Keep as is.
#define PIPE_FENCE() __builtin_amdgcn_sched_barrier(0)

// ===========================================================================
// Generic big-P 1x1 conv, 1D grid, depth-D double-buffered pipeline.
// swz=0 natural; swz=1 z-stripe (enc1); swz=2 (b,xb)-group stripe (dec3).
//   enc1: OT=8  D=8, nx=4 ny=4,  256 blocks, swz=1.
//   dec3: OT=16 D=4, nx=4 ny=16, 512 blocks, swz=2.
// ===========================================================================
template<int OT, int D, bool HASBN, bool HASSTATS>
__global__ __launch_bounds__(256,2) void conv1x1_kernel(
    const float* __restrict__ in0, const float* __restrict__ in1,
    const float* __restrict__ w, float* __restrict__ out,
    const float* __restrict__ stIn, float* __restrict__ stOut,
    int I, int O, int P, int wio, int zsplit, float invN,
    int nx, int ny, int swz)
{
  __shared__ float wl[2048];
  __shared__ float bnm[256], bnr[256];
  int tid = threadIdx.x;

  int bid = blockIdx.x;
  int nb  = nx*ny;          // blocks per z
  int xb, yb, z;
  if(swz == 1){
    int xcd = bid & 7, slot = bid >> 3;
    int zl = slot/nb, inner = slot - zl*nb;
    xb = inner % nx; yb = inner / nx; z = xcd + 8*zl;
  } else if(swz == 2){
    int xcd = bid & 7, slot = bid >> 3;
    int gq = slot / ny, m = slot - gq*ny;
    int g  = xcd + 8*gq;
    xb = g % nx; z = g / nx; yb = m;
  } else {
    int zq = bid / nb, inner = bid - zq*nb;
    xb = inner % nx; yb = inner / nx; z = zq;
  }

  int o0 = yb*OT;
  int t  = (z >= zsplit) ? 1 : 0;
  int b  = t ? (z - zsplit) : z;
  const float* in = t ? in1 : in0;

  for(int idx=tid; idx<I*OT; idx+=256){
    int i = idx/OT, j = idx - i*OT;
    wl[idx] = wio ? w[(size_t)i*O + o0 + j] : w[(size_t)(o0+j)*I + i];
  }
  if(HASBN){
    for(int i=tid; i<I; i+=256){
      float s  = stIn[((size_t)t*I + i)*2];
      float s2 = stIn[((size_t)t*I + i)*2+1];
      float m  = s*invN;
      bnm[i] = m;
      bnr[i] = rsqrtf(s2*invN - m*m + EPS_BN);
    }
  }
  __syncthreads();

  int p4 = xb*256 + tid;
  const float4* inb = (const float4*)(in + (size_t)b*I*P) + p4;
  int P4 = P >> 2;

  float acc[OT][4];
#pragma unroll
  for(int j=0;j<OT;j++){ acc[j][0]=acc[j][1]=acc[j][2]=acc[j][3]=0.f; }

  auto consume = [&](const float4* vv, int i0){
#pragma unroll
    for(int u=0;u<D;u++){
      float4 v = vv[u];
      if(HASBN){
        float m = bnm[i0+u], r = bnr[i0+u];
        v.x = fmaxf((v.x-m)*r, 0.f); v.y = fmaxf((v.y-m)*r, 0.f);
        v.z = fmaxf((v.z-m)*r, 0.f); v.w = fmaxf((v.w-m)*r, 0.f);
      }
      const float* wr = &wl[(i0+u)*OT];
#pragma unroll
      for(int j=0;j<OT;j++){
        float wv = wr[j];
        acc[j][0] = fmaf(wv, v.x, acc[j][0]);
        acc[j][1] = fmaf(wv, v.y, acc[j][1]);
        acc[j][2] = fmaf(wv, v.z, acc[j][2]);
        acc[j][3] = fmaf(wv, v.w, acc[j][3]);
      }
    }
  };

  float4 va[D], vb[D];
#pragma unroll
  for(int u=0;u<D;u++) va[u] = inb[(size_t)u*P4];
  PIPE_FENCE();

  for(int i0=0;i0<I;i0+=2*D){
#pragma unroll
    for(int u=0;u<D;u++) vb[u] = inb[(size_t)(i0+D+u)*P4];
    PIPE_FENCE();
    consume(va, i0);
    if(i0+2*D < I){
#pragma unroll
      for(int u=0;u<D;u++) va[u] = inb[(size_t)(i0+2*D+u)*P4];
    }
    PIPE_FENCE();
    consume(vb, i0+D);
  }

  float4* ob = (float4*)(out + ((size_t)z*O + o0)*P) + p4;
#pragma unroll
  for(int j=0;j<OT;j++){
    float4 vv = {acc[j][0], acc[j][1], acc[j][2], acc[j][3]};
    ob[(size_t)j*P4] = vv;
  }

  if(HASSTATS){
#pragma unroll
    for(int j=0;j<OT;j++){
      float s  = acc[j][0]+acc[j][1]+acc[j][2]+acc[j][3];
      float s2 = acc[j][0]*acc[j][0]+acc[j][1]*acc[j][1]
               + acc[j][2]*acc[j][2]+acc[j][3]*acc[j][3];
      for(int off=32; off>0; off>>=1){
        s  += __shfl_down(s,  off, 64);
        s2 += __shfl_down(s2, off, 64);
      }
      if((tid & 63)==0){
        atomicAdd(&stOut[((size_t)t*O + o0 + j)*2],   s);
        atomicAdd(&stOut[((size_t)t*O + o0 + j)*2+1], s2);
      }
    }
  }
}

// ===========================================================================
// Small-P (P=1024) 1x1 conv: 128 f4-cols x 2 o-slices. 8-deep pipeline.
// ===========================================================================
template<int OT, bool HASBN, bool HASSTATS>
__global__ __launch_bounds__(256) void conv1x1_small(
    const float* __restrict__ in0, const float* __restrict__ in1,
    const float* __restrict__ w, float* __restrict__ out,
    const float* __restrict__ stIn, float* __restrict__ stOut,
    int I, int O, int wio, int zsplit, float invN)
{
  __shared__ float wl[512];
  __shared__ float bnm[128], bnr[128];
  int tid = threadIdx.x;
  int z  = blockIdx.z;
  int t  = (z >= zsplit) ? 1 : 0;
  int b  = t ? (z - zsplit) : z;
  const float* in = t ? in1 : in0;
  int W2 = 2*OT;

  for(int idx=tid; idx<I*W2; idx+=256){
    int i = idx/W2, slot = idx - i*W2;
    int oabs = blockIdx.y*W2 + slot;
    wl[idx] = wio ? w[(size_t)i*O + oabs] : w[(size_t)oabs*I + i];
  }
  if(HASBN){
    for(int i=tid; i<I; i+=256){
      float s  = stIn[((size_t)t*I + i)*2];
      float s2 = stIn[((size_t)t*I + i)*2+1];
      float m  = s*invN;
      bnm[i] = m;
      bnr[i] = rsqrtf(s2*invN - m*m + EPS_BN);
    }
  }
  __syncthreads();

  int p4 = blockIdx.x*128 + (tid & 127);
  int os = tid >> 7;
  const float4* inb = (const float4*)(in + (size_t)b*I*1024) + p4;

  float acc[OT][4];
#pragma unroll
  for(int j=0;j<OT;j++){ acc[j][0]=acc[j][1]=acc[j][2]=acc[j][3]=0.f; }

  float4 vb[8];
  for(int i0=0;i0<I;i0+=8){
#pragma unroll
    for(int u=0;u<8;u++) vb[u] = inb[(size_t)(i0+u)*256];
    PIPE_FENCE();
#pragma unroll
    for(int u=0;u<8;u++){
      float4 v = vb[u];
      if(HASBN){
        float m = bnm[i0+u], r = bnr[i0+u];
        v.x = fmaxf((v.x-m)*r, 0.f); v.y = fmaxf((v.y-m)*r, 0.f);
        v.z = fmaxf((v.z-m)*r, 0.f); v.w = fmaxf((v.w-m)*r, 0.f);
      }
      const float* wr = &wl[(i0+u)*W2 + os*OT];
#pragma unroll
      for(int j=0;j<OT;j++){
        float wv = wr[j];
        acc[j][0] = fmaf(wv, v.x, acc[j][0]);
        acc[j][1] = fmaf(wv, v.y, acc[j][1]);
        acc[j][2] = fmaf(wv, v.z, acc[j][2]);
        acc[j][3] = fmaf(wv, v.w, acc[j][3]);
      }
    }
  }

  int obase = blockIdx.y*W2 + os*OT;
  float4* ob = (float4*)(out + ((size_t)z*O + obase)*1024) + p4;
#pragma unroll
  for(int j=0;j<OT;j++){
    float4 vv = {acc[j][0], acc[j][1], acc[j][2], acc[j][3]};
    ob[(size_t)j*256] = vv;
  }

  if(HASSTATS){
#pragma unroll
    for(int j=0;j<OT;j++){
      float s  = acc[j][0]+acc[j][1]+acc[j][2]+acc[j][3];
      float s2 = acc[j][0]*acc[j][0]+acc[j][1]*acc[j][1]
               + acc[j][2]*acc[j][2]+acc[j][3]*acc[j][3];
      for(int off=32; off>0; off>>=1){
        s  += __shfl_down(s,  off, 64);
        s2 += __shfl_down(s2, off, 64);
      }
      if((tid & 63)==0){
        atomicAdd(&stOut[((size_t)t*O + obase + j)*2],   s);
        atomicAdd(&stOut[((size_t)t*O + obase + j)*2+1], s2);
      }
    }
  }
}

// ===========================================================================
// Encoder k=2 s=2 conv (unchanged)
// ===========================================================================
__global__ __launch_bounds__(256) void conv2x2s2_bn_kernel(
    const float* __restrict__ in, const float* __restrict__ w,
    float* __restrict__ out, const float* __restrict__ stIn,
    float* __restrict__ stOut, float invN)
{
  __shared__ float wl[512];
  __shared__ float bnm[32], bnr[32];
  int tid = threadIdx.x;
  int o0 = blockIdx.x*4;
  int rq = blockIdx.y;
  int z  = blockIdx.z;
  int t  = z >> 3;

  for(int idx=tid; idx<512; idx+=256){
    int osub = idx>>7, ch=(idx>>2)&31, pq=idx&3;
    wl[idx] = w[(((size_t)(o0+osub)*32 + ch)*4) + pq];
  }
  if(tid < 32){
    float s  = stIn[((size_t)t*32 + tid)*2];
    float s2 = stIn[((size_t)t*32 + tid)*2+1];
    float m  = s*invN;
    bnm[tid] = m;
    bnr[tid] = rsqrtf(s2*invN - m*m + EPS_BN);
  }
  __syncthreads();

  int os   = tid >> 6;
  int slot = tid & 63;
  int h    = rq*8 + (slot>>3);
  int wg   = slot & 7;
  int cb   = wg*8;
  const float* wbase = &wl[os*128];
  const float* inz = in + (size_t)z*32*4096;

  float acc[4] = {0,0,0,0};
  float4 c0,c1,c2,c3, n0_,n1_,n2_,n3_;
  c0 = *(const float4*)(inz + (size_t)0*4096 + (2*h)*64 + cb);
  c1 = *(const float4*)(inz + (size_t)0*4096 + (2*h)*64 + cb + 4);
  c2 = *(const float4*)(inz + (size_t)0*4096 + (2*h+1)*64 + cb);
  c3 = *(const float4*)(inz + (size_t)0*4096 + (2*h+1)*64 + cb + 4);
  for(int ch=0; ch<32; ch++){
    if(ch < 31){
      n0_ = *(const float4*)(inz + (size_t)(ch+1)*4096 + (2*h)*64 + cb);
      n1_ = *(const float4*)(inz + (size_t)(ch+1)*4096 + (2*h)*64 + cb + 4);
      n2_ = *(const float4*)(inz + (size_t)(ch+1)*4096 + (2*h+1)*64 + cb);
      n3_ = *(const float4*)(inz + (size_t)(ch+1)*4096 + (2*h+1)*64 + cb + 4);
    }
    float m = bnm[ch], r = bnr[ch];
    float t0[8] = {c0.x,c0.y,c0.z,c0.w,c1.x,c1.y,c1.z,c1.w};
    float t1[8] = {c2.x,c2.y,c2.z,c2.w,c3.x,c3.y,c3.z,c3.w};
#pragma unroll
    for(int e=0;e<8;e++){
      t0[e] = fmaxf((t0[e]-m)*r, 0.f);
      t1[e] = fmaxf((t1[e]-m)*r, 0.f);
    }
    const float* wp = wbase + ch*4;
#pragma unroll
    for(int k=0;k<4;k++){
      acc[k] = fmaf(wp[0], t0[2*k],   acc[k]);
      acc[k] = fmaf(wp[1], t0[2*k+1], acc[k]);
      acc[k] = fmaf(wp[2], t1[2*k],   acc[k]);
      acc[k] = fmaf(wp[3], t1[2*k+1], acc[k]);
    }
    c0=n0_; c1=n1_; c2=n2_; c3=n3_;
  }

  float4 vv = {acc[0],acc[1],acc[2],acc[3]};
  *(float4*)(out + ((size_t)z*32 + o0+os)*1024 + h*32 + wg*4) = vv;

  float s  = acc[0]+acc[1]+acc[2]+acc[3];
  float s2 = acc[0]*acc[0]+acc[1]*acc[1]+acc[2]*acc[2]+acc[3]*acc[3];
  for(int off=32; off>0; off>>=1){
    s  += __shfl_down(s,  off, 64);
    s2 += __shfl_down(s2, off, 64);
  }
  if((tid & 63)==0){
    atomicAdd(&stOut[((size_t)t*32 + o0 + os)*2],   s);
    atomicAdd(&stOut[((size_t)t*32 + o0 + os)*2+1], s2);
  }
}

// ===========================================================================
// ConvTranspose k=2 s=2 (pipeline fence)
// ===========================================================================
__global__ __launch_bounds__(256) void upsample2x2_bn_kernel(
    const float* __restrict__ in, const float* __restrict__ w,
    float* __restrict__ out, const float* __restrict__ stIn,
    float* __restrict__ stOut, float invN)
{
  __shared__ float wl[1024];
  __shared__ float bnm[128], bnr[128];
  int tid = threadIdx.x;
  int o0 = blockIdx.x*2;
  int b  = blockIdx.y;

  for(int idx=tid; idx<1024; idx+=256){
    int pq = idx & 3, r = idx >> 2;
    int i = r >> 1, j = r & 1;
    wl[idx] = w[((size_t)i*128 + o0+j)*4 + pq];
  }
  if(tid < 128){
    float s  = stIn[(size_t)tid*2];
    float s2 = stIn[(size_t)tid*2+1];
    float m  = s*invN;
    bnm[tid] = m;
    bnr[tid] = rsqrtf(s2*invN - m*m + EPS_BN);
  }
  __syncthreads();

  int h  = tid >> 3;
  int wg = tid & 7;
  int w0 = wg*4;

  float acc[2][16];
#pragma unroll
  for(int j=0;j<2;j++) for(int e=0;e<16;e++) acc[j][e]=0.f;

  float4 vb4[8];
  for(int i0=0;i0<128;i0+=8){
#pragma unroll
    for(int u=0;u<8;u++)
      vb4[u] = *(const float4*)(in + (((size_t)b*128+i0+u)*1024) + h*32 + w0);
    PIPE_FENCE();
#pragma unroll
    for(int u=0;u<8;u++){
      int i = i0+u;
      float4 v = vb4[u];
      float m = bnm[i], r = bnr[i];
      float vk[4] = {fmaxf((v.x-m)*r,0.f), fmaxf((v.y-m)*r,0.f),
                     fmaxf((v.z-m)*r,0.f), fmaxf((v.w-m)*r,0.f)};
#pragma unroll
      for(int j=0;j<2;j++){
        const float* wj = &wl[(i*2+j)*4];
#pragma unroll
        for(int pq=0;pq<4;pq++){
#pragma unroll
          for(int k=0;k<4;k++)
            acc[j][pq*4+k] = fmaf(wj[pq], vk[k], acc[j][pq*4+k]);
        }
      }
    }
  }

#pragma unroll
  for(int j=0;j<2;j++){
    float* ob = out + ((size_t)b*128 + o0+j)*4096;
#pragma unroll
    for(int p=0;p<2;p++){
      float4 A = {acc[j][(p*2+0)*4+0], acc[j][(p*2+1)*4+0],
                  acc[j][(p*2+0)*4+1], acc[j][(p*2+1)*4+1]};
      float4 B = {acc[j][(p*2+0)*4+2], acc[j][(p*2+1)*4+2],
                  acc[j][(p*2+0)*4+3], acc[j][(p*2+1)*4+3]};
      *(float4*)(ob + (2*h+p)*64 + 2*w0)     = A;
      *(float4*)(ob + (2*h+p)*64 + 2*w0 + 4) = B;
    }
  }

#pragma unroll
  for(int j=0;j<2;j++){
    float s=0.f, s2=0.f;
#pragma unroll
    for(int e=0;e<16;e++){ s += acc[j][e]; s2 += acc[j][e]*acc[j][e]; }
    for(int off=32; off>0; off>>=1){
      s  += __shfl_down(s,  off, 64);
      s2 += __shfl_down(s2, off, 64);
    }
    if((tid & 63)==0){
      atomicAdd(&stOut[((size_t)(o0+j))*2],   s);
      atomicAdd(&stOut[((size_t)(o0+j))*2+1], s2);
    }
  }
}

// ===========================================================================
__global__ __launch_bounds__(256) void bn_final_kernel(
    float* __restrict__ x, const float* __restrict__ st, float invN)
{
  int idx4 = blockIdx.x*256 + threadIdx.x;
  int c = (idx4 >> 10) & 255;
  float s  = st[(size_t)c*2];
  float s2 = st[(size_t)c*2+1];
  float m  = s*invN;
  float r  = rsqrtf(s2*invN - m*m + EPS_BN);
  float4 v = ((float4*)x)[idx4];
  v.x = fmaxf((v.x-m)*r, 0.f); v.y = fmaxf((v.y-m)*r, 0.f);
  v.z = fmaxf((v.z-m)*r, 0.f); v.w = fmaxf((v.w-m)*r, 0.f);
  ((float4*)x)[idx4] = v;
}

// ===========================================================================
// depthwise 3x3, pad 1, f4 per thread, whole 32x32 per (c,b). grid (C,B).
// ===========================================================================
__global__ __launch_bounds__(256) void dwconv3x3_kernel(
    const float* __restrict__ in, const float* __restrict__ w,
    float* __restrict__ out, int C)
{
  int c = blockIdx.x, b = blockIdx.y;
  int tid = threadIdx.x;
  __shared__ float wl[9];
  if(tid < 9) wl[tid] = w[c*9 + tid];
  __syncthreads();
  int h = tid >> 3, x4 = tid & 7;
  int c0 = x4*4;
  const float* base = in + ((size_t)b*C + c)*1024;
  float ax=0.f, ay=0.f, az=0.f, aw=0.f;
#pragma unroll
  for(int dr=0; dr<3; dr++){
    int r = h + dr - 1;
    if((unsigned)r >= 32u) continue;
    const float* row = base + r*32 + c0;
    float4 cc = *(const float4*)row;
    float l  = (x4>0) ? row[-1] : 0.f;
    float rr = (x4<7) ? row[4]  : 0.f;
    float w0=wl[dr*3], w1=wl[dr*3+1], w2=wl[dr*3+2];
    ax = fmaf(w0,l,   fmaf(w1,cc.x, fmaf(w2,cc.y, ax)));
    ay = fmaf(w0,cc.x,fmaf(w1,cc.y, fmaf(w2,cc.z, ay)));
    az = fmaf(w0,cc.y,fmaf(w1,cc.z, fmaf(w2,cc.w, az)));
    aw = fmaf(w0,cc.z,fmaf(w1,cc.w, fmaf(w2,rr,  aw)));
  }
  float4 vv = {ax,ay,az,aw};
  *(float4*)(out + ((size_t)b*C + c)*1024 + h*32 + c0) = vv;
}

// ===========================================================================
// full 3x3 conv, pad 1, f4 per thread, whole 32x32 per (o,b). grid (O,B).
// ===========================================================================
__global__ __launch_bounds__(256) void conv3x3_kernel(
    const float* __restrict__ in, const float* __restrict__ w,
    float* __restrict__ out, int IC)
{
  int o = blockIdx.x, b = blockIdx.y;
  int tid = threadIdx.x;
  __shared__ float wl[576];
  for(int t=tid; t<IC*9; t+=256) wl[t] = w[(size_t)o*IC*9 + t];
  __syncthreads();
  int h = tid >> 3, x4 = tid & 7;
  int c0 = x4*4;
  const float* inb = in + (size_t)b*IC*1024;
  float ax=0.f, ay=0.f, az=0.f, aw=0.f;
#pragma unroll 2
  for(int i=0;i<IC;i++){
    const float* base = inb + (size_t)i*1024;
    const float* wp = &wl[i*9];
#pragma unroll
    for(int dr=0; dr<3; dr++){
      int r = h + dr - 1;
      if((unsigned)r >= 32u) continue;
      const float* row = base + r*32 + c0;
      float4 cc = *(const float4*)row;
      float l  = (x4>0) ? row[-1] : 0.f;
      float rr = (x4<7) ? row[4]  : 0.f;
      float w0=wp[dr*3], w1=wp[dr*3+1], w2=wp[dr*3+2];
      ax = fmaf(w0,l,   fmaf(w1,cc.x, fmaf(w2,cc.y, ax)));
      ay = fmaf(w0,cc.x,fmaf(w1,cc.y, fmaf(w2,cc.z, ay)));
      az = fmaf(w0,cc.y,fmaf(w1,cc.z, fmaf(w2,cc.w, az)));
      aw = fmaf(w0,cc.z,fmaf(w1,cc.w, fmaf(w2,rr,  aw)));
    }
  }
  float4 vv = {ax,ay,az,aw};
  *(float4*)(out + ((size_t)b*gridDim.x + o)*1024 + h*32 + c0) = vv;
}

// ===========================================================================
// Row norms only: scl[r] = 1/max(||row||,1e-12). r<512: q rows; else k rows.
// ===========================================================================
__global__ __launch_bounds__(256) void norm_scale_kernel(
    const float* __restrict__ q, const float* __restrict__ kv,
    float* __restrict__ scl)
{
  int r = blockIdx.x;
  const float* p;
  if(r < 512){ int b=r>>6, c=r&63; p = q + ((size_t)b*64+c)*1024; }
  else { int rr=r-512; int b=rr>>6, c=rr&63; p = kv + ((size_t)b*128+c)*1024; }
  int tid = threadIdx.x;
  float4 v = ((const float4*)p)[tid];
  float s = v.x*v.x + v.y*v.y + v.z*v.z + v.w*v.w;
  __shared__ float ls[256];
  ls[tid]=s; __syncthreads();
  for(int st=128; st>0; st>>=1){ if(tid<st) ls[tid]+=ls[tid+st]; __syncthreads(); }
  if(tid==0) scl[r] = 1.f/fmaxf(sqrtf(ls[0]), 1e-12f);
}

// ===========================================================================
// Spatial attention pass 1 (norm scales applied on load). grid (16,8,8).
// ===========================================================================
__global__ __launch_bounds__(256) void attn_pass1(
    const float* __restrict__ q, const float* __restrict__ kv,
    const float* __restrict__ temp, const float* __restrict__ scl,
    float* __restrict__ den_out)
{
  int bx = blockIdx.x, hh = blockIdx.y, b = blockIdx.z;
  int nchunk = bx >> 2, mq = bx & 3;
  int tid = threadIdx.x;
  __shared__ __align__(16) float kl[256*12];
  const float* kb = kv + ((size_t)b*128 + hh*8)*1024 + mq*256;
  for(int t=tid;t<2048;t+=256){
    int c=t>>8, m=t&255;
    kl[m*12+c] = kb[(size_t)c*1024+m] * scl[512 + b*64 + hh*8 + c];
  }
  __syncthreads();
  int n = nchunk*256 + tid;
  const float* qp = q + ((size_t)b*64 + hh*8)*1024 + n;
  float th = temp[hh];
  float mxb = fabsf(th);
  float qr[8];
#pragma unroll
  for(int c=0;c<8;c++) qr[c] = qp[(size_t)c*1024] * scl[b*64+hh*8+c] * th;
  const float4* kl4 = (const float4*)kl;
  float den = 0.f, den2 = 0.f;
  for(int m=0;m<256;m+=2){
    float4 a  = kl4[m*3],     a2 = kl4[m*3+1];
    float4 bt = kl4[(m+1)*3], b2 = kl4[(m+1)*3+1];
    float s0 = qr[0]*a.x+qr[1]*a.y+qr[2]*a.z+qr[3]*a.w
             + qr[4]*a2.x+qr[5]*a2.y+qr[6]*a2.z+qr[7]*a2.w;
    float s1 = qr[0]*bt.x+qr[1]*bt.y+qr[2]*bt.z+qr[3]*bt.w
             + qr[4]*b2.x+qr[5]*b2.y+qr[6]*b2.z+qr[7]*b2.w;
    den  += __expf(s0 - mxb);
    den2 += __expf(s1 - mxb);
  }
  atomicAdd(&den_out[((size_t)(b*8+hh))*1024+n], den+den2);
}

// ===========================================================================
// Spatial attention pass 2 (norm scales applied on load). grid (16,8,8).
// ===========================================================================
__global__ __launch_bounds__(256) void attn_pass2(
    const float* __restrict__ q, const float* __restrict__ kv,
    const float* __restrict__ temp, const float* __restrict__ scl,
    const float* __restrict__ den, float* __restrict__ out)
{
  int bx = blockIdx.x, hh = blockIdx.y, b = blockIdx.z;
  int mchunk = bx >> 2, nq = bx & 3;
  int tid = threadIdx.x;
  __shared__ __align__(16) float ql[256*12];
  __shared__ __align__(16) float vl[256*12];
  __shared__ float idl[256];
  int bh = b*8+hh;
  int n0 = nq*256;
  const float* qb = q  + ((size_t)b*64 + hh*8)*1024 + n0;
  const float* vb = kv + ((size_t)b*128 + 64 + hh*8)*1024 + n0;
  for(int t=tid;t<2048;t+=256){
    int c=t>>8, n=t&255;
    ql[n*12+c] = qb[(size_t)c*1024+n] * scl[b*64+hh*8+c];
    vl[n*12+c] = vb[(size_t)c*1024+n];
  }
  idl[tid] = 1.f/den[(size_t)bh*1024 + n0 + tid];
  __syncthreads();
  int m = mchunk*256 + tid;
  const float* kb = kv + ((size_t)b*128 + hh*8)*1024 + m;
  float th = temp[hh];
  float mxb = fabsf(th);
  float kr[8];
#pragma unroll
  for(int c=0;c<8;c++) kr[c] = kb[(size_t)c*1024] * scl[512+b*64+hh*8+c] * th;
  float acc[8] = {0,0,0,0,0,0,0,0};
  const float4* ql4 = (const float4*)ql;
  const float4* vl4 = (const float4*)vl;
  for(int n=0;n<256;n+=2){
    float4 qa = ql4[n*3],     qa2 = ql4[n*3+1];
    float4 qc = ql4[(n+1)*3], qc2 = ql4[(n+1)*3+1];
    float s0 = kr[0]*qa.x+kr[1]*qa.y+kr[2]*qa.z+kr[3]*qa.w
             + kr[4]*qa2.x+kr[5]*qa2.y+kr[6]*qa2.z+kr[7]*qa2.w;
    float s1 = kr[0]*qc.x+kr[1]*qc.y+kr[2]*qc.z+kr[3]*qc.w
             + kr[4]*qc2.x+kr[5]*qc2.y+kr[6]*qc2.z+kr[7]*qc2.w;
    float p0 = __expf(s0 - mxb) * idl[n];
    float p1 = __expf(s1 - mxb) * idl[n+1];
    float4 va = vl4[n*3],     va2 = vl4[n*3+1];
    float4 vc = vl4[(n+1)*3], vc2 = vl4[(n+1)*3+1];
    acc[0]+=p0*va.x + p1*vc.x; acc[1]+=p0*va.y + p1*vc.y;
    acc[2]+=p0*va.z + p1*vc.z; acc[3]+=p0*va.w + p1*vc.w;
    acc[4]+=p0*va2.x + p1*vc2.x; acc[5]+=p0*va2.y + p1*vc2.y;
    acc[6]+=p0*va2.z + p1*vc2.z; acc[7]+=p0*va2.w + p1*vc2.w;
  }
  float* ob = out + ((size_t)b*64 + hh*8)*1024 + m;
#pragma unroll
  for(int c=0;c<8;c++) atomicAdd(&ob[(size_t)c*1024], acc[c]);
}

// ===========================================================================
// Channel attention; gram scaled by qs[c]*ks[d]*t post-reduction.
// grid (8,8,4): nq = n-quarter; PV phase 4x parallel.
// ===========================================================================
__global__ __launch_bounds__(256) void attn_channel(
    const float* __restrict__ q, const float* __restrict__ kv,
    const float* __restrict__ temp, const float* __restrict__ scl,
    float* out)
{
  int hh = blockIdx.x, b = blockIdx.y, nq = blockIdx.z;
  __shared__ float kl[8192];
  const float* qb = q  + ((size_t)b*64 + hh*8)*1024;
  const float* kb = kv + ((size_t)b*128 + hh*8)*1024;
  const float* vb = kv + ((size_t)b*128 + 64 + hh*8)*1024;
  int tid = threadIdx.x;
  for(int t=tid;t<8192;t+=256) kl[t]=kb[t];
  __syncthreads();
  __shared__ float part[256];
  __shared__ float a[64];
  {
    int pair = tid >> 2, seg = tid & 3;
    int c = pair >> 3, d = pair & 7;
    const float* qrow = qb + (size_t)c*1024 + seg*256;
    const float* krow = kl + d*1024 + seg*256;
    float s = 0.f;
#pragma unroll 4
    for(int n=0;n<256;n++) s += qrow[n]*krow[n];
    part[tid] = s;
  }
  __syncthreads();
  if(tid < 64){
    int c = tid >> 3, d = tid & 7;
    float g = part[tid*4]+part[tid*4+1]+part[tid*4+2]+part[tid*4+3];
    part[tid] = g * scl[b*64+hh*8+c] * scl[512+b*64+hh*8+d] * temp[hh];
  }
  __syncthreads();
  if(tid < 8){
    float mx = -3.4e38f;
    for(int d=0;d<8;d++) mx = fmaxf(mx, part[tid*8+d]);
    float den = 0.f;
    float e[8];
    for(int d=0;d<8;d++){ e[d] = __expf(part[tid*8+d]-mx); den+=e[d]; }
    float inv = 1.f/den;
    for(int d=0;d<8;d++) a[tid*8+d] = e[d]*inv;
  }
  __syncthreads();
  float* ob = out + ((size_t)b*64 + hh*8)*1024;
  {
    int n = nq*256 + tid;
    float vv[8];
#pragma unroll
    for(int d=0;d<8;d++) vv[d] = vb[(size_t)d*1024+n];
#pragma unroll
    for(int c=0;c<8;c++){
      float s = 0.f;
#pragma unroll
      for(int d=0;d<8;d++) s += a[c*8+d]*vv[d];
      ob[(size_t)c*1024+n] += s;
    }
  }
}

// ===========================================================================
extern "C" void kernel_launch(void* const* d_in, const int* in_sizes, int n_in,
                              void* d_out, int out_size, void* d_ws, size_t ws_size,
                              hipStream_t stream)
{
  (void)in_sizes; (void)n_in; (void)out_size; (void)ws_size;
  const float* x      = (const float*)d_in[0];
  const float* y      = (const float*)d_in[1];
  const float* temp   = (const float*)d_in[2];
  const float* enc_w1 = (const float*)d_in[3];
  const float* enc_w2 = (const float*)d_in[4];
  const float* enc_w3 = (const float*)d_in[5];
  const float* kv_w   = (const float*)d_in[6];
  const float* kv_dw_w= (const float*)d_in[7];
  const float* q_w    = (const float*)d_in[8];
  const float* q_dw_w = (const float*)d_in[9];
  const float* proj_w = (const float*)d_in[10];
  const float* dec_w1 = (const float*)d_in[11];
  const float* dec_w2 = (const float*)d_in[12];
  const float* dec_w3 = (const float*)d_in[13];
  float* out = (float*)d_out;

  float* W   = (float*)d_ws;
  float* ST  = W;                    // 2048
  float* ST0 = ST;
  float* ST1 = ST + 128;
  float* ST2 = ST + 256;
  float* ST3 = ST + 512;
  float* ST4 = ST + 768;
  float* ST5 = ST + 1024;
  float* A    = W + 2048;            // 2,097,152-float region, multiply reused
  float* E1   = A;
  float* KV1  = A;
  float* QPre = A + 1048576;
  float* ATTN = A;
  float* PROJ = A + 524288;
  float* D1   = A + 1048576;
  float* E2   = W + 2099200;         //   524,288
  float* E3   = W + 2623488;         // 1,048,576
  float* KV   = W + 3672064;         // 1,048,576
  float* Q    = W + 4720640;         //   524,288
  float* SCL  = W + 5244928;         //     1,024 (q/k reciprocal norms)
  float* DEN  = W + 5245952;         //    65,536
  float* D2   = W + 2099200;         // 4,194,304 (overlaps E2..DEN, dead then)

  const float inv32k = 1.f/32768.f, inv8k = 1.f/8192.f;

  hipMemsetAsync(ST, 0, 2048*sizeof(float), stream);
  hipMemsetAsync(DEN, 0, 65536*sizeof(float), stream);

  // ---- encoder ----
  conv1x1_kernel<8,8,false,true><<<256,256,0,stream>>>(
      x, y, enc_w1, E1, nullptr, ST0, 256, 32, 4096, 0, 8, 0.f,
      /*nx=*/4, /*ny=*/4, /*swz=*/1);
  conv2x2s2_bn_kernel<<<dim3(8,4,16),256,0,stream>>>(E1, enc_w2, E2, ST0, ST1, inv32k);
  conv1x1_small<1,true,true><<<dim3(2,32,16),256,0,stream>>>(
      E2, E2 + (size_t)8*32*1024, enc_w3, E3, ST1, ST2, 32, 64, 0, 8, inv8k);

  // ---- kv = dw3x3(1x1(x_enc)); q = conv3x3(1x1(y_enc)) ----
  conv1x1_small<1,true,false><<<dim3(2,64,8),256,0,stream>>>(
      E3, E3, kv_w, KV1, ST2, nullptr, 64, 128, 0, 999, inv8k);
  dwconv3x3_kernel<<<dim3(128,8),256,0,stream>>>(KV1, kv_dw_w, KV, 128);
  conv1x1_small<1,true,false><<<dim3(2,32,8),256,0,stream>>>(
      E3 + (size_t)8*64*1024, E3, q_w, QPre, ST2 + 128, nullptr, 64, 64, 0, 999, inv8k);
  conv3x3_kernel<<<dim3(64,8),256,0,stream>>>(QPre, q_dw_w, Q, 64);

  // ATTN region (overlapping KV1/QPre) dead now — zero for atomics
  hipMemsetAsync(ATTN, 0, 524288*sizeof(float), stream);

  // ---- q/k row norms (scales only; tensors stay raw) ----
  norm_scale_kernel<<<1024,256,0,stream>>>(Q, KV, SCL);

  // ---- attention ----
  attn_pass1<<<dim3(16,8,8),256,0,stream>>>(Q, KV, temp, SCL, DEN);
  attn_pass2<<<dim3(16,8,8),256,0,stream>>>(Q, KV, temp, SCL, DEN, ATTN);
  attn_channel<<<dim3(8,8,4),256,0,stream>>>(Q, KV, temp, SCL, ATTN);

  // ---- proj ----
  conv1x1_small<1,false,false><<<dim3(2,32,8),256,0,stream>>>(
      ATTN, ATTN, proj_w, PROJ, nullptr, nullptr, 64, 64, 0, 999, 0.f);

  // ---- decoder ----
  conv1x1_small<1,false,true><<<dim3(2,64,8),256,0,stream>>>(
      PROJ, PROJ, dec_w1, D1, nullptr, ST3, 64, 128, 1, 999, 0.f);
  upsample2x2_bn_kernel<<<dim3(64,8),256,0,stream>>>(D1, dec_w2, D2, ST3, ST4, inv8k);
  conv1x1_kernel<16,4,true,true><<<512,256,0,stream>>>(
      D2, D2, dec_w3, out, ST4, ST5, 128, 256, 4096, 1, 999, inv32k,
      /*nx=*/4, /*ny=*/16, /*swz=*/2);
  bn_final_kernel<<<8192,256,0,stream>>>(out, ST5, inv32k);
}